// Round 9
// baseline (242.429 us; speedup 1.0000x reference)
//
#include <hip/hip_runtime.h>

typedef unsigned short u16;
typedef unsigned int   u32;
typedef unsigned long long u64;

#define HID 128
#define KPB 256      // keys per coarse bucket (shift 8)
#define NBMAX 512    // max coarse buckets (actual: 391)
#define IPB 2048     // incidences per partition workgroup
#define CAP 6144     // LDS val-staging capacity per bucket (mean ~3070)
#define LSTRIDE 136  // LDS row stride (u16) for the fused h-tile

typedef __bf16 bf16x8 __attribute__((ext_vector_type(8)));
typedef float  f32x4  __attribute__((ext_vector_type(4)));

__device__ inline float u2f(u32 u){ union{u32 u;float f;} v; v.u=u; return v.f; }
__device__ inline u32   f2u(float f){ union{float f;u32 u;} v; v.f=f; return v.u; }
__device__ inline u32  f2bfu(float f){ u32 b=f2u(f); return ((b + 0x7FFFu + ((b>>16)&1u))>>16)&0xFFFFu; }
__device__ inline float blo(u32 u){ return u2f(u<<16); }
__device__ inline float bhi(u32 u){ return u2f(u & 0xFFFF0000u); }
__device__ inline u32  pk(float lo, float hi){ return (f2bfu(hi)<<16) | f2bfu(lo); }

// ---------- branch-free 16-row gather-accumulate (zero pad row at index zrow) ----------
// Issues all 16 dwordx4 loads back-to-back; out-of-window lanes read the zero row.
__device__ inline void gather16(const u32* __restrict__ tab, int myc, int gbase, int c,
                                int lim, int zrow,
                                float&a0,float&a1,float&a2,float&a3,
                                float&a4,float&a5,float&a6,float&a7){
    int src[16];
    #pragma unroll
    for (int i=0;i<16;++i){
        int s = __shfl(myc, gbase|i, 64);
        src[i] = (i < lim) ? s : zrow;
    }
    uint4 v[16];
    #pragma unroll
    for (int i=0;i<16;++i)
        v[i] = *reinterpret_cast<const uint4*>(tab + (size_t)src[i]*64 + (c<<2));
    #pragma unroll
    for (int i=0;i<16;++i){
        a0 += blo(v[i].x); a1 += bhi(v[i].x);
        a2 += blo(v[i].y); a3 += bhi(v[i].y);
        a4 += blo(v[i].z); a5 += bhi(v[i].z);
        a6 += blo(v[i].w); a7 += bhi(v[i].w);
    }
}

// ---------- K1: coarse histogram (blocks [0,nhb)) ∪ W-fragment conversion ∪ pad-row zeroing ----------
__global__ __launch_bounds__(256) void k_hist_wfrag(const int* __restrict__ nidx, const int* __restrict__ eidx,
                                                    int* __restrict__ hist, int nE, int nN, int nb, int nhb,
                                                    const float* __restrict__ W1, const float* __restrict__ W2,
                                                    u16* __restrict__ W1f, u16* __restrict__ W2f,
                                                    u32* __restrict__ padB, u32* __restrict__ padC){
    __shared__ int h[NBMAX];
    if ((int)blockIdx.x < nhb){
        for (int t=threadIdx.x; t<nb; t+=256) h[t]=0;
        __syncthreads();
        int base = blockIdx.x*IPB;
        for (int k=threadIdx.x; k<IPB; k+=256){
            int j = base+k;
            if (j < nE){
                atomicAdd(&h[nidx[j]>>8], 1);
                atomicAdd(&h[(nN+eidx[j])>>8], 1);
            }
        }
        __syncthreads();
        for (int t=threadIdx.x; t<nb; t+=256) if (h[t]) atomicAdd(&hist[t], h[t]);
    } else if ((int)blockIdx.x < nhb + 128){
        int gid = ((int)blockIdx.x - nhb)*256 + threadIdx.x;   // 32768 total
        const float* W = (gid < 16384) ? W1 : W2;
        u16* Wf = (gid < 16384) ? W1f : W2f;
        int id = gid & 16383;
        int i = id & 7, l = (id>>3)&63, j = (id>>9)&7, s = id>>12;
        Wf[id] = (u16)f2bfu(W[(s*32 + ((l>>4)<<3) + i)*HID + (j<<4) + (l&15)]);
    } else {
        int t = threadIdx.x;
        if (t < 64)       padB[t]      = 0u;   // zero pad row of bufB (row nN, 64 u32)
        else if (t < 128) padC[t - 64] = 0u;   // zero pad row of bufC
    }
}

// ---------- K2: partition into buckets (blocks [0,npb)) ∪ layer-1 GEMM fp32-A (rest) ----------
__global__ __launch_bounds__(256) void k_part_gemm(const int* __restrict__ nidx, const int* __restrict__ eidx,
                                                   const int* __restrict__ hist, int* __restrict__ bfill,
                                                   u64* __restrict__ pairs, int nE, int nN, int nb, int npb,
                                                   const float* __restrict__ A, const u16* __restrict__ Wf,
                                                   u16* __restrict__ C, int M){
    __shared__ int h[NBMAX], rsv[NBMAX], fl[NBMAX], bb[NBMAX], sd[256];
    int t = threadIdx.x;
    if ((int)blockIdx.x < npb){
        for (int i=t; i<nb; i+=256){ h[i]=0; fl[i]=0; }
        __syncthreads();
        int base = blockIdx.x*IPB;
        for (int k=t; k<IPB; k+=256){
            int j = base+k;
            if (j < nE){
                atomicAdd(&h[nidx[j]>>8], 1);
                atomicAdd(&h[(nN+eidx[j])>>8], 1);
            }
        }
        int c0 = (2*t   < nb) ? hist[2*t]   : 0;
        int c1 = (2*t+1 < nb) ? hist[2*t+1] : 0;
        int s = c0 + c1;
        sd[t] = s; __syncthreads();
        for (int o=1;o<256;o<<=1){ int u = (t>=o)? sd[t-o] : 0; __syncthreads(); sd[t]+=u; __syncthreads(); }
        int ex = sd[t] - s;
        if (2*t   < nb) bb[2*t]   = ex;
        if (2*t+1 < nb) bb[2*t+1] = ex + c0;
        __syncthreads();
        for (int i=t; i<nb; i+=256){ if (h[i]) rsv[i] = bb[i] + atomicAdd(&bfill[i], h[i]); }
        __syncthreads();
        for (int k=t; k<IPB; k+=256){
            int j = base+k;
            if (j < nE){
                int n = nidx[j], e = eidx[j];
                int b1 = n>>8;
                int p1 = rsv[b1] + atomicAdd(&fl[b1], 1);
                pairs[p1] = ((u64)(u32)n << 32) | (u32)e;
                int k2 = nN + e;
                int b2 = k2>>8;
                int p2 = rsv[b2] + atomicAdd(&fl[b2], 1);
                pairs[p2] = ((u64)(u32)k2 << 32) | (u32)n;
            }
        }
    } else {
        int wave = ((int)blockIdx.x - npb)*4 + (t>>6);
        int lane = t & 63;
        int rtiles = M >> 4;
        if (wave >= rtiles) return;
        int row0 = wave << 4;
        const float* Arow = A + (size_t)(row0 + (lane&15))*HID + ((lane>>4)<<3);
        const bf16x8* Wp = reinterpret_cast<const bf16x8*>(Wf) + lane;
        f32x4 acc[8];
        #pragma unroll
        for (int j=0;j<8;++j) acc[j] = (f32x4){0.f,0.f,0.f,0.f};
        #pragma unroll
        for (int s=0;s<4;++s){
            float4 f0 = *reinterpret_cast<const float4*>(Arow + s*32);
            float4 f1 = *reinterpret_cast<const float4*>(Arow + s*32 + 4);
            union { u16 h[8]; bf16x8 v; } au;
            au.h[0]=(u16)f2bfu(f0.x); au.h[1]=(u16)f2bfu(f0.y); au.h[2]=(u16)f2bfu(f0.z); au.h[3]=(u16)f2bfu(f0.w);
            au.h[4]=(u16)f2bfu(f1.x); au.h[5]=(u16)f2bfu(f1.y); au.h[6]=(u16)f2bfu(f1.z); au.h[7]=(u16)f2bfu(f1.w);
            #pragma unroll
            for (int j=0;j<8;++j){
                bf16x8 b = Wp[(s*8 + j)*64];
                acc[j] = __builtin_amdgcn_mfma_f32_16x16x32_bf16(au.v, b, acc[j], 0, 0, 0);
            }
        }
        int r0 = row0 + ((lane>>4)<<2);
        int c0 = lane & 15;
        #pragma unroll
        for (int j=0;j<8;++j){
            #pragma unroll
            for (int r=0;r<4;++r){
                C[(size_t)(r0+r)*HID + j*16 + c0] = (u16)f2bfu(acc[j][r]);
            }
        }
    }
}

// ---------- per-bucket fine counting sort in LDS ----------
__global__ __launch_bounds__(256) void k_bucket(const u64* __restrict__ pairs, const int* __restrict__ hist,
                                                int* __restrict__ csr, int* __restrict__ off,
                                                int nkeys, int nb, int total){
    __shared__ int cntS[KPB];
    __shared__ int fillS[KPB];
    __shared__ int bbS[NBMAX+1];
    __shared__ int sd[256];
    __shared__ int vals[CAP];
    int b = blockIdx.x;
    int t = threadIdx.x;
    if (b == 0 && t == 0) off[nkeys] = total;
    int c0 = (2*t   < nb) ? hist[2*t]   : 0;
    int c1 = (2*t+1 < nb) ? hist[2*t+1] : 0;
    int s = c0 + c1;
    sd[t] = s; __syncthreads();
    for (int o=1;o<256;o<<=1){ int u = (t>=o)? sd[t-o] : 0; __syncthreads(); sd[t]+=u; __syncthreads(); }
    int ex = sd[t] - s;
    if (2*t   <= nb) bbS[2*t]   = ex;
    if (2*t+1 <= nb) bbS[2*t+1] = ex + c0;
    __syncthreads();
    int base = bbS[b];
    int n = bbS[b+1] - base;
    int k0 = b * KPB;

    cntS[t] = 0;
    __syncthreads();
    for (int i=t; i<n; i+=256){
        u64 p = pairs[base+i];
        atomicAdd(&cntS[(int)(p>>32) - k0], 1);
    }
    __syncthreads();
    int c = cntS[t];
    __syncthreads();
    fillS[t] = c; __syncthreads();
    for (int o=1;o<256;o<<=1){ int u = (t>=o)? fillS[t-o] : 0; __syncthreads(); fillS[t]+=u; __syncthreads(); }
    int ex2 = fillS[t] - c;
    __syncthreads();
    fillS[t] = ex2;
    __syncthreads();
    int k = k0 + t;
    if (k < nkeys) off[k] = base + ex2;
    bool fits = (n <= CAP);
    for (int i=t; i<n; i+=256){
        u64 p = pairs[base+i];
        int kl = (int)(p>>32) - k0;
        int pos = atomicAdd(&fillS[kl], 1);
        if (fits) vals[pos] = (int)(u32)p;
        else      csr[base+pos] = (int)(u32)p;
    }
    __syncthreads();
    if (fits){
        for (int i=t; i<n; i+=256) csr[base+i] = vals[i];
    }
}

// ---------- CSR-gather segment mean: one dest row per 16-lane group, branch-free loads ----------
// MODE 0: out bf16, scale only | MODE 2: fp32 out, + bias + resid + prelu
template<int MODE>
__global__ __launch_bounds__(256) void k_agg(const u32* __restrict__ tab, const int* __restrict__ csr,
                                             const int* __restrict__ off, void* __restrict__ outp,
                                             const float* __restrict__ bias, const float* __restrict__ resid,
                                             const float* __restrict__ aptr, int nrows, int zrow){
    int lane = threadIdx.x & 63;
    int g = lane >> 4, c = lane & 15;
    int d = blockIdx.x*16 + ((threadIdx.x>>6)<<2) + g;
    if (d >= nrows) return;
    int start = off[d], end = off[d+1];
    int deg = end - start;
    int gbase = g << 4;

    float a0=0.f,a1=0.f,a2=0.f,a3=0.f,a4=0.f,a5=0.f,a6=0.f,a7=0.f;
    for (int pos = start; pos < end; pos += 16){
        int myc = csr[pos + c];
        gather16(tab, myc, gbase, c, end - pos, zrow, a0,a1,a2,a3,a4,a5,a6,a7);
    }
    float s = (deg > 0) ? 1.0f/(float)deg : 0.f;
    a0*=s; a1*=s; a2*=s; a3*=s; a4*=s; a5*=s; a6*=s; a7*=s;
    if constexpr (MODE == 2){
        float4 b0 = *reinterpret_cast<const float4*>(bias + (c<<3));
        float4 b1v = *reinterpret_cast<const float4*>(bias + (c<<3) + 4);
        a0+=b0.x; a1+=b0.y; a2+=b0.z; a3+=b0.w;
        a4+=b1v.x; a5+=b1v.y; a6+=b1v.z; a7+=b1v.w;
        const float* rp = resid + (size_t)d*HID + (c<<3);
        float4 r0 = *reinterpret_cast<const float4*>(rp);
        float4 r1 = *reinterpret_cast<const float4*>(rp + 4);
        a0+=r0.x; a1+=r0.y; a2+=r0.z; a3+=r0.w;
        a4+=r1.x; a5+=r1.y; a6+=r1.z; a7+=r1.w;
        float al = aptr[0];
        a0 = (a0>=0.f)? a0 : al*a0;  a1 = (a1>=0.f)? a1 : al*a1;
        a2 = (a2>=0.f)? a2 : al*a2;  a3 = (a3>=0.f)? a3 : al*a3;
        a4 = (a4>=0.f)? a4 : al*a4;  a5 = (a5>=0.f)? a5 : al*a5;
        a6 = (a6>=0.f)? a6 : al*a6;  a7 = (a7>=0.f)? a7 : al*a7;
        float* op = (float*)outp + (size_t)d*HID + (c<<3);
        *reinterpret_cast<float4*>(op)     = make_float4(a0,a1,a2,a3);
        *reinterpret_cast<float4*>(op + 4) = make_float4(a4,a5,a6,a7);
    } else {
        uint4 wv;
        wv.x = pk(a0,a1); wv.y = pk(a2,a3); wv.z = pk(a4,a5); wv.w = pk(a6,a7);
        *reinterpret_cast<uint4*>((u32*)outp + (size_t)d*64 + (c<<2)) = wv;
    }
}

// ---------- FUSED: agg MODE-1 (gather + scale + bias + prelu -> 16x128 h-tile in LDS)
//            + 16x128 @ 128x128 MFMA GEMM (each wave: 2 column tiles) -> C = h @ W2 ----------
__global__ __launch_bounds__(256) void k_agg1_gemm(const u32* __restrict__ tab, const int* __restrict__ csr,
                                                   const int* __restrict__ off, u16* __restrict__ C,
                                                   const float* __restrict__ bias, const float* __restrict__ aptr,
                                                   const u16* __restrict__ Wf, int nrows, int zrow){
    __shared__ u16 hS[16*LSTRIDE];
    int t = threadIdx.x;
    int lane = t & 63;
    int wv = t >> 6;
    int g = lane >> 4, c = lane & 15;
    int r = (wv<<2) + g;              // local row 0..15
    int d = blockIdx.x*16 + r;
    int gbase = g << 4;

    float a0=0.f,a1=0.f,a2=0.f,a3=0.f,a4=0.f,a5=0.f,a6=0.f,a7=0.f;
    if (d < nrows){
        int start = off[d], end = off[d+1];
        int deg = end - start;
        for (int pos = start; pos < end; pos += 16){
            int myc = csr[pos + c];
            gather16(tab, myc, gbase, c, end - pos, zrow, a0,a1,a2,a3,a4,a5,a6,a7);
        }
        float s = (deg > 0) ? 1.0f/(float)deg : 0.f;
        a0*=s; a1*=s; a2*=s; a3*=s; a4*=s; a5*=s; a6*=s; a7*=s;
        float4 b0 = *reinterpret_cast<const float4*>(bias + (c<<3));
        float4 b1v = *reinterpret_cast<const float4*>(bias + (c<<3) + 4);
        a0+=b0.x; a1+=b0.y; a2+=b0.z; a3+=b0.w;
        a4+=b1v.x; a5+=b1v.y; a6+=b1v.z; a7+=b1v.w;
        float al = aptr[0];
        a0 = (a0>=0.f)? a0 : al*a0;  a1 = (a1>=0.f)? a1 : al*a1;
        a2 = (a2>=0.f)? a2 : al*a2;  a3 = (a3>=0.f)? a3 : al*a3;
        a4 = (a4>=0.f)? a4 : al*a4;  a5 = (a5>=0.f)? a5 : al*a5;
        a6 = (a6>=0.f)? a6 : al*a6;  a7 = (a7>=0.f)? a7 : al*a7;
    }
    {
        uint4 wv4;
        wv4.x = pk(a0,a1); wv4.y = pk(a2,a3); wv4.z = pk(a4,a5); wv4.w = pk(a6,a7);
        *reinterpret_cast<uint4*>((u32*)(hS + (size_t)r*LSTRIDE) + (c<<2)) = wv4;
    }
    __syncthreads();

    const u16* Arow = hS + (size_t)(lane&15)*LSTRIDE + ((lane>>4)<<3);
    const bf16x8* Wp = reinterpret_cast<const bf16x8*>(Wf) + lane;
    f32x4 acc0 = (f32x4){0.f,0.f,0.f,0.f}, acc1 = acc0;
    #pragma unroll
    for (int s=0;s<4;++s){
        bf16x8 a = *reinterpret_cast<const bf16x8*>(Arow + s*32);
        bf16x8 bA = Wp[(s*8 + 2*wv    )*64];
        bf16x8 bB = Wp[(s*8 + 2*wv + 1)*64];
        acc0 = __builtin_amdgcn_mfma_f32_16x16x32_bf16(a, bA, acc0, 0, 0, 0);
        acc1 = __builtin_amdgcn_mfma_f32_16x16x32_bf16(a, bB, acc1, 0, 0, 0);
    }
    int r0 = (lane>>4)<<2;
    int c0 = lane & 15;
    #pragma unroll
    for (int rr=0;rr<4;++rr){
        int row = blockIdx.x*16 + r0 + rr;
        if (row < nrows){
            C[(size_t)row*HID + (2*wv  )*16 + c0] = (u16)f2bfu(acc0[rr]);
            C[(size_t)row*HID + (2*wv+1)*16 + c0] = (u16)f2bfu(acc1[rr]);
        }
    }
}

extern "C" void kernel_launch(void* const* d_in, const int* in_sizes, int n_in,
                              void* d_out, int out_size, void* d_ws, size_t ws_size,
                              hipStream_t stream){
    (void)n_in; (void)out_size; (void)ws_size;
    const float* x  = (const float*)d_in[0];
    const int*  hei = (const int*)  d_in[1];
    const float* W1 = (const float*)d_in[2];
    const float* b1 = (const float*)d_in[3];
    const float* W2 = (const float*)d_in[4];
    const float* b2 = (const float*)d_in[5];
    const float* ap = (const float*)d_in[6];

    const int nN = in_sizes[0] / HID;   // 50000
    const int nE = in_sizes[1] / 2;     // 600000
    const int* nidx = hei;
    const int* eidx = hei + nE;
    const int nkeys = 2*nN;
    const int nb    = (nkeys + KPB - 1) / KPB;   // 391

    char* w = (char*)d_ws;
    size_t o = 0;
    auto alloc = [&](size_t bytes)->void*{
        void* p = (void*)(w + o);
        o += (bytes + 255) & ~(size_t)255;
        return p;
    };
    int* hist  = (int*)alloc((size_t)NBMAX*sizeof(int));
    int* bfill = (int*)alloc((size_t)NBMAX*sizeof(int));
    int* off   = (int*)alloc(((size_t)nkeys+1)*sizeof(int));
    int* csr   = (int*)alloc((size_t)2*nE*sizeof(int));
    u64* pairs = (u64*)alloc((size_t)2*nE*sizeof(u64));
    u16* bufB  = (u16*)alloc((size_t)(nN+1)*HID*sizeof(u16));   // xw / hw (+ zero pad row nN)
    u16* bufC  = (u16*)alloc((size_t)(nN+1)*HID*sizeof(u16));   // m / m2 (+ zero pad row nN)
    u16* w1f   = (u16*)alloc((size_t)HID*HID*sizeof(u16));
    u16* w2f   = (u16*)alloc((size_t)HID*HID*sizeof(u16));

    hipMemsetAsync(hist, 0, (size_t)2*NBMAX*sizeof(int), stream);   // hist + bfill (contiguous)

    const int pgrid  = (nE + IPB - 1)/IPB;       // 293
    const int rtiles = nN/16;                    // 3125
    const int ggrid  = (rtiles + 3)/4;           // 782

    u32* padB = (u32*)(bufB + (size_t)nN*HID);
    u32* padC = (u32*)(bufC + (size_t)nN*HID);

    // K1: hist ∪ wfrag ∪ pad-row zeroing
    k_hist_wfrag<<<pgrid + 129, 256, 0, stream>>>(nidx, eidx, hist, nE, nN, nb, pgrid,
                                                  W1, W2, w1f, w2f, padB, padC);
    // K2: part ∪ layer-1 gemm (fp32 A)
    k_part_gemm<<<pgrid + ggrid, 256, 0, stream>>>(nidx, eidx, hist, bfill, pairs, nE, nN, nb, pgrid,
                                                   x, w1f, bufB, nN);
    // K3: bucket (also writes off sentinel)
    k_bucket<<<nb, 256, 0, stream>>>(pairs, hist, csr, off, nkeys, nb, 2*nE);

    const int agrid = (nN + 15)/16;              // 3125

    // layer 1
    k_agg<0><<<agrid, 256, 0, stream>>>((const u32*)bufB, csr, off + nN, bufC, nullptr, nullptr, nullptr, nN, nN);
    // fused: agg MODE-1 (h) + h @ W2 -> bufB
    k_agg1_gemm<<<agrid, 256, 0, stream>>>((const u32*)bufC, csr, off, bufB, b1, ap, w2f, nN, nN);
    // layer 2
    k_agg<0><<<agrid, 256, 0, stream>>>((const u32*)bufB, csr, off + nN, bufC, nullptr, nullptr, nullptr, nN, nN);
    k_agg<2><<<agrid, 256, 0, stream>>>((const u32*)bufC, csr, off, d_out, b2, x, ap, nN, nN);
}

// Round 10
// 225.230 us; speedup vs baseline: 1.0764x; 1.0764x over previous
//
#include <hip/hip_runtime.h>

typedef unsigned short u16;
typedef unsigned int   u32;
typedef unsigned long long u64;

#define HID 128
#define KPB 256      // keys per coarse bucket (shift 8)
#define NBMAX 512    // max coarse buckets (actual: 391)
#define IPB 2048     // incidences per partition workgroup
#define CAP 6144     // LDS val-staging capacity per bucket (mean ~3070)
#define LSTRIDE 136  // LDS row stride (u16) for the fused h-tile: breaks pow-2 bank pattern

typedef __bf16 bf16x8 __attribute__((ext_vector_type(8)));
typedef float  f32x4  __attribute__((ext_vector_type(4)));

__device__ inline float u2f(u32 u){ union{u32 u;float f;} v; v.u=u; return v.f; }
__device__ inline u32   f2u(float f){ union{float f;u32 u;} v; v.f=f; return v.u; }
__device__ inline u32  f2bfu(float f){ u32 b=f2u(f); return ((b + 0x7FFFu + ((b>>16)&1u))>>16)&0xFFFFu; }
__device__ inline float blo(u32 u){ return u2f(u<<16); }
__device__ inline float bhi(u32 u){ return u2f(u & 0xFFFF0000u); }
__device__ inline u32  pk(float lo, float hi){ return (f2bfu(hi)<<16) | f2bfu(lo); }

// ---------- K1: coarse histogram (blocks [0,nhb)) ∪ W-fragment conversion (rest) ----------
__global__ __launch_bounds__(256) void k_hist_wfrag(const int* __restrict__ nidx, const int* __restrict__ eidx,
                                                    int* __restrict__ hist, int nE, int nN, int nb, int nhb,
                                                    const float* __restrict__ W1, const float* __restrict__ W2,
                                                    u16* __restrict__ W1f, u16* __restrict__ W2f){
    __shared__ int h[NBMAX];
    if ((int)blockIdx.x < nhb){
        for (int t=threadIdx.x; t<nb; t+=256) h[t]=0;
        __syncthreads();
        int base = blockIdx.x*IPB;
        for (int k=threadIdx.x; k<IPB; k+=256){
            int j = base+k;
            if (j < nE){
                atomicAdd(&h[nidx[j]>>8], 1);
                atomicAdd(&h[(nN+eidx[j])>>8], 1);
            }
        }
        __syncthreads();
        for (int t=threadIdx.x; t<nb; t+=256) if (h[t]) atomicAdd(&hist[t], h[t]);
    } else {
        int gid = ((int)blockIdx.x - nhb)*256 + threadIdx.x;   // 32768 total
        const float* W = (gid < 16384) ? W1 : W2;
        u16* Wf = (gid < 16384) ? W1f : W2f;
        int id = gid & 16383;
        int i = id & 7, l = (id>>3)&63, j = (id>>9)&7, s = id>>12;
        Wf[id] = (u16)f2bfu(W[(s*32 + ((l>>4)<<3) + i)*HID + (j<<4) + (l&15)]);
    }
}

// ---------- K2: partition into buckets (blocks [0,npb)) ∪ layer-1 GEMM fp32-A (rest) ----------
__global__ __launch_bounds__(256) void k_part_gemm(const int* __restrict__ nidx, const int* __restrict__ eidx,
                                                   const int* __restrict__ hist, int* __restrict__ bfill,
                                                   u64* __restrict__ pairs, int nE, int nN, int nb, int npb,
                                                   const float* __restrict__ A, const u16* __restrict__ Wf,
                                                   u16* __restrict__ C, int M){
    __shared__ int h[NBMAX], rsv[NBMAX], fl[NBMAX], bb[NBMAX], sd[256];
    int t = threadIdx.x;
    if ((int)blockIdx.x < npb){
        for (int i=t; i<nb; i+=256){ h[i]=0; fl[i]=0; }
        __syncthreads();
        int base = blockIdx.x*IPB;
        for (int k=t; k<IPB; k+=256){
            int j = base+k;
            if (j < nE){
                atomicAdd(&h[nidx[j]>>8], 1);
                atomicAdd(&h[(nN+eidx[j])>>8], 1);
            }
        }
        int c0 = (2*t   < nb) ? hist[2*t]   : 0;
        int c1 = (2*t+1 < nb) ? hist[2*t+1] : 0;
        int s = c0 + c1;
        sd[t] = s; __syncthreads();
        for (int o=1;o<256;o<<=1){ int u = (t>=o)? sd[t-o] : 0; __syncthreads(); sd[t]+=u; __syncthreads(); }
        int ex = sd[t] - s;
        if (2*t   < nb) bb[2*t]   = ex;
        if (2*t+1 < nb) bb[2*t+1] = ex + c0;
        __syncthreads();
        for (int i=t; i<nb; i+=256){ if (h[i]) rsv[i] = bb[i] + atomicAdd(&bfill[i], h[i]); }
        __syncthreads();
        for (int k=t; k<IPB; k+=256){
            int j = base+k;
            if (j < nE){
                int n = nidx[j], e = eidx[j];
                int b1 = n>>8;
                int p1 = rsv[b1] + atomicAdd(&fl[b1], 1);
                pairs[p1] = ((u64)(u32)n << 32) | (u32)e;
                int k2 = nN + e;
                int b2 = k2>>8;
                int p2 = rsv[b2] + atomicAdd(&fl[b2], 1);
                pairs[p2] = ((u64)(u32)k2 << 32) | (u32)n;
            }
        }
    } else {
        int wave = ((int)blockIdx.x - npb)*4 + (t>>6);
        int lane = t & 63;
        int rtiles = M >> 4;
        if (wave >= rtiles) return;
        int row0 = wave << 4;
        const float* Arow = A + (size_t)(row0 + (lane&15))*HID + ((lane>>4)<<3);
        const bf16x8* Wp = reinterpret_cast<const bf16x8*>(Wf) + lane;
        f32x4 acc[8];
        #pragma unroll
        for (int j=0;j<8;++j) acc[j] = (f32x4){0.f,0.f,0.f,0.f};
        #pragma unroll
        for (int s=0;s<4;++s){
            float4 f0 = *reinterpret_cast<const float4*>(Arow + s*32);
            float4 f1 = *reinterpret_cast<const float4*>(Arow + s*32 + 4);
            union { u16 h[8]; bf16x8 v; } au;
            au.h[0]=(u16)f2bfu(f0.x); au.h[1]=(u16)f2bfu(f0.y); au.h[2]=(u16)f2bfu(f0.z); au.h[3]=(u16)f2bfu(f0.w);
            au.h[4]=(u16)f2bfu(f1.x); au.h[5]=(u16)f2bfu(f1.y); au.h[6]=(u16)f2bfu(f1.z); au.h[7]=(u16)f2bfu(f1.w);
            #pragma unroll
            for (int j=0;j<8;++j){
                bf16x8 b = Wp[(s*8 + j)*64];
                acc[j] = __builtin_amdgcn_mfma_f32_16x16x32_bf16(au.v, b, acc[j], 0, 0, 0);
            }
        }
        int r0 = row0 + ((lane>>4)<<2);
        int c0 = lane & 15;
        #pragma unroll
        for (int j=0;j<8;++j){
            #pragma unroll
            for (int r=0;r<4;++r){
                C[(size_t)(r0+r)*HID + j*16 + c0] = (u16)f2bfu(acc[j][r]);
            }
        }
    }
}

// ---------- per-bucket fine counting sort in LDS (computes own base locally) ----------
__global__ __launch_bounds__(256) void k_bucket(const u64* __restrict__ pairs, const int* __restrict__ hist,
                                                int* __restrict__ csr, int* __restrict__ off,
                                                int nkeys, int nb, int total){
    __shared__ int cntS[KPB];
    __shared__ int fillS[KPB];
    __shared__ int bbS[NBMAX+1];
    __shared__ int sd[256];
    __shared__ int vals[CAP];
    int b = blockIdx.x;
    int t = threadIdx.x;
    if (b == 0 && t == 0) off[nkeys] = total;
    int c0 = (2*t   < nb) ? hist[2*t]   : 0;
    int c1 = (2*t+1 < nb) ? hist[2*t+1] : 0;
    int s = c0 + c1;
    sd[t] = s; __syncthreads();
    for (int o=1;o<256;o<<=1){ int u = (t>=o)? sd[t-o] : 0; __syncthreads(); sd[t]+=u; __syncthreads(); }
    int ex = sd[t] - s;
    if (2*t   <= nb) bbS[2*t]   = ex;
    if (2*t+1 <= nb) bbS[2*t+1] = ex + c0;
    __syncthreads();
    int base = bbS[b];
    int n = bbS[b+1] - base;
    int k0 = b * KPB;

    cntS[t] = 0;
    __syncthreads();
    for (int i=t; i<n; i+=256){
        u64 p = pairs[base+i];
        atomicAdd(&cntS[(int)(p>>32) - k0], 1);
    }
    __syncthreads();
    int c = cntS[t];
    __syncthreads();
    fillS[t] = c; __syncthreads();
    for (int o=1;o<256;o<<=1){ int u = (t>=o)? fillS[t-o] : 0; __syncthreads(); fillS[t]+=u; __syncthreads(); }
    int ex2 = fillS[t] - c;
    __syncthreads();
    fillS[t] = ex2;
    __syncthreads();
    int k = k0 + t;
    if (k < nkeys) off[k] = base + ex2;
    bool fits = (n <= CAP);
    for (int i=t; i<n; i+=256){
        u64 p = pairs[base+i];
        int kl = (int)(p>>32) - k0;
        int pos = atomicAdd(&fillS[kl], 1);
        if (fits) vals[pos] = (int)(u32)p;
        else      csr[base+pos] = (int)(u32)p;
    }
    __syncthreads();
    if (fits){
        for (int i=t; i<n; i+=256) csr[base+i] = vals[i];
    }
}

// ---------- CSR-gather segment mean: one dest row per 16-lane group (4 rows/wave) ----------
// MODE 0: out bf16, scale only | MODE 2: fp32 out, + bias + resid + prelu
template<int MODE>
__global__ __launch_bounds__(256) void k_agg(const u32* __restrict__ tab, const int* __restrict__ csr,
                                             const int* __restrict__ off, void* __restrict__ outp,
                                             const float* __restrict__ bias, const float* __restrict__ resid,
                                             const float* __restrict__ aptr, int nrows){
    int lane = threadIdx.x & 63;
    int g = lane >> 4, c = lane & 15;
    int d = blockIdx.x*16 + ((threadIdx.x>>6)<<2) + g;
    if (d >= nrows) return;
    int start = off[d], end = off[d+1];
    int deg = end - start;
    int gbase = g << 4;

    float a0=0.f,a1=0.f,a2=0.f,a3=0.f,a4=0.f,a5=0.f,a6=0.f,a7=0.f;
    for (int pos = start; pos < end; pos += 16){
        int myc = csr[pos + c];
        int lim = end - pos;
        #pragma unroll
        for (int i=0;i<16;i+=4){
            int s0 = __shfl(myc, gbase|i,     64);
            int s1 = __shfl(myc, gbase|(i+1), 64);
            int s2 = __shfl(myc, gbase|(i+2), 64);
            int s3 = __shfl(myc, gbase|(i+3), 64);
            uint4 v0 = make_uint4(0u,0u,0u,0u), v1 = v0, v2 = v0, v3 = v0;
            if (i   < lim) v0 = *reinterpret_cast<const uint4*>(tab + (size_t)s0*64 + (c<<2));
            if (i+1 < lim) v1 = *reinterpret_cast<const uint4*>(tab + (size_t)s1*64 + (c<<2));
            if (i+2 < lim) v2 = *reinterpret_cast<const uint4*>(tab + (size_t)s2*64 + (c<<2));
            if (i+3 < lim) v3 = *reinterpret_cast<const uint4*>(tab + (size_t)s3*64 + (c<<2));
            a0 += blo(v0.x)+blo(v1.x)+blo(v2.x)+blo(v3.x);
            a1 += bhi(v0.x)+bhi(v1.x)+bhi(v2.x)+bhi(v3.x);
            a2 += blo(v0.y)+blo(v1.y)+blo(v2.y)+blo(v3.y);
            a3 += bhi(v0.y)+bhi(v1.y)+bhi(v2.y)+bhi(v3.y);
            a4 += blo(v0.z)+blo(v1.z)+blo(v2.z)+blo(v3.z);
            a5 += bhi(v0.z)+bhi(v1.z)+bhi(v2.z)+bhi(v3.z);
            a6 += blo(v0.w)+blo(v1.w)+blo(v2.w)+blo(v3.w);
            a7 += bhi(v0.w)+bhi(v1.w)+bhi(v2.w)+bhi(v3.w);
        }
    }
    float s = (deg > 0) ? 1.0f/(float)deg : 0.f;
    a0*=s; a1*=s; a2*=s; a3*=s; a4*=s; a5*=s; a6*=s; a7*=s;
    if constexpr (MODE == 2){
        float4 b0 = *reinterpret_cast<const float4*>(bias + (c<<3));
        float4 b1v = *reinterpret_cast<const float4*>(bias + (c<<3) + 4);
        a0+=b0.x; a1+=b0.y; a2+=b0.z; a3+=b0.w;
        a4+=b1v.x; a5+=b1v.y; a6+=b1v.z; a7+=b1v.w;
        const float* rp = resid + (size_t)d*HID + (c<<3);
        float4 r0 = *reinterpret_cast<const float4*>(rp);
        float4 r1 = *reinterpret_cast<const float4*>(rp + 4);
        a0+=r0.x; a1+=r0.y; a2+=r0.z; a3+=r0.w;
        a4+=r1.x; a5+=r1.y; a6+=r1.z; a7+=r1.w;
        float al = aptr[0];
        a0 = (a0>=0.f)? a0 : al*a0;  a1 = (a1>=0.f)? a1 : al*a1;
        a2 = (a2>=0.f)? a2 : al*a2;  a3 = (a3>=0.f)? a3 : al*a3;
        a4 = (a4>=0.f)? a4 : al*a4;  a5 = (a5>=0.f)? a5 : al*a5;
        a6 = (a6>=0.f)? a6 : al*a6;  a7 = (a7>=0.f)? a7 : al*a7;
        float* op = (float*)outp + (size_t)d*HID + (c<<3);
        *reinterpret_cast<float4*>(op)     = make_float4(a0,a1,a2,a3);
        *reinterpret_cast<float4*>(op + 4) = make_float4(a4,a5,a6,a7);
    } else {
        uint4 wv;
        wv.x = pk(a0,a1); wv.y = pk(a2,a3); wv.z = pk(a4,a5); wv.w = pk(a6,a7);
        *reinterpret_cast<uint4*>((u32*)outp + (size_t)d*64 + (c<<2)) = wv;
    }
}

// ---------- FUSED: agg MODE-1 (gather + scale + bias + prelu -> 16x128 h-tile in LDS)
//            + 16x128 @ 128x128 MFMA GEMM (each wave: 2 column tiles) -> C = h @ W2 ----------
__global__ __launch_bounds__(256) void k_agg1_gemm(const u32* __restrict__ tab, const int* __restrict__ csr,
                                                   const int* __restrict__ off, u16* __restrict__ C,
                                                   const float* __restrict__ bias, const float* __restrict__ aptr,
                                                   const u16* __restrict__ Wf, int nrows){
    __shared__ u16 hS[16*LSTRIDE];
    int t = threadIdx.x;
    int lane = t & 63;
    int wv = t >> 6;
    int g = lane >> 4, c = lane & 15;
    int r = (wv<<2) + g;              // local row 0..15
    int d = blockIdx.x*16 + r;
    int gbase = g << 4;

    float a0=0.f,a1=0.f,a2=0.f,a3=0.f,a4=0.f,a5=0.f,a6=0.f,a7=0.f;
    if (d < nrows){
        int start = off[d], end = off[d+1];
        int deg = end - start;
        for (int pos = start; pos < end; pos += 16){
            int myc = csr[pos + c];
            int lim = end - pos;
            #pragma unroll
            for (int i=0;i<16;i+=4){
                int s0 = __shfl(myc, gbase|i,     64);
                int s1 = __shfl(myc, gbase|(i+1), 64);
                int s2 = __shfl(myc, gbase|(i+2), 64);
                int s3 = __shfl(myc, gbase|(i+3), 64);
                uint4 v0 = make_uint4(0u,0u,0u,0u), v1 = v0, v2 = v0, v3 = v0;
                if (i   < lim) v0 = *reinterpret_cast<const uint4*>(tab + (size_t)s0*64 + (c<<2));
                if (i+1 < lim) v1 = *reinterpret_cast<const uint4*>(tab + (size_t)s1*64 + (c<<2));
                if (i+2 < lim) v2 = *reinterpret_cast<const uint4*>(tab + (size_t)s2*64 + (c<<2));
                if (i+3 < lim) v3 = *reinterpret_cast<const uint4*>(tab + (size_t)s3*64 + (c<<2));
                a0 += blo(v0.x)+blo(v1.x)+blo(v2.x)+blo(v3.x);
                a1 += bhi(v0.x)+bhi(v1.x)+bhi(v2.x)+bhi(v3.x);
                a2 += blo(v0.y)+blo(v1.y)+blo(v2.y)+blo(v3.y);
                a3 += bhi(v0.y)+bhi(v1.y)+bhi(v2.y)+bhi(v3.y);
                a4 += blo(v0.z)+blo(v1.z)+blo(v2.z)+blo(v3.z);
                a5 += bhi(v0.z)+bhi(v1.z)+bhi(v2.z)+bhi(v3.z);
                a6 += blo(v0.w)+blo(v1.w)+blo(v2.w)+blo(v3.w);
                a7 += bhi(v0.w)+bhi(v1.w)+bhi(v2.w)+bhi(v3.w);
            }
        }
        float s = (deg > 0) ? 1.0f/(float)deg : 0.f;
        a0*=s; a1*=s; a2*=s; a3*=s; a4*=s; a5*=s; a6*=s; a7*=s;
        float4 b0 = *reinterpret_cast<const float4*>(bias + (c<<3));
        float4 b1v = *reinterpret_cast<const float4*>(bias + (c<<3) + 4);
        a0+=b0.x; a1+=b0.y; a2+=b0.z; a3+=b0.w;
        a4+=b1v.x; a5+=b1v.y; a6+=b1v.z; a7+=b1v.w;
        float al = aptr[0];
        a0 = (a0>=0.f)? a0 : al*a0;  a1 = (a1>=0.f)? a1 : al*a1;
        a2 = (a2>=0.f)? a2 : al*a2;  a3 = (a3>=0.f)? a3 : al*a3;
        a4 = (a4>=0.f)? a4 : al*a4;  a5 = (a5>=0.f)? a5 : al*a5;
        a6 = (a6>=0.f)? a6 : al*a6;  a7 = (a7>=0.f)? a7 : al*a7;
    }
    // stage h row (bf16) into LDS
    {
        uint4 wv4;
        wv4.x = pk(a0,a1); wv4.y = pk(a2,a3); wv4.z = pk(a4,a5); wv4.w = pk(a6,a7);
        *reinterpret_cast<uint4*>((u32*)(hS + (size_t)r*LSTRIDE) + (c<<2)) = wv4;
    }
    __syncthreads();

    // MFMA: wave wv computes column tiles j = 2*wv, 2*wv+1 of C[block rows] = h @ W2
    const u16* Arow = hS + (size_t)(lane&15)*LSTRIDE + ((lane>>4)<<3);
    const bf16x8* Wp = reinterpret_cast<const bf16x8*>(Wf) + lane;
    f32x4 acc0 = (f32x4){0.f,0.f,0.f,0.f}, acc1 = acc0;
    #pragma unroll
    for (int s=0;s<4;++s){
        bf16x8 a = *reinterpret_cast<const bf16x8*>(Arow + s*32);
        bf16x8 bA = Wp[(s*8 + 2*wv    )*64];
        bf16x8 bB = Wp[(s*8 + 2*wv + 1)*64];
        acc0 = __builtin_amdgcn_mfma_f32_16x16x32_bf16(a, bA, acc0, 0, 0, 0);
        acc1 = __builtin_amdgcn_mfma_f32_16x16x32_bf16(a, bB, acc1, 0, 0, 0);
    }
    int r0 = (lane>>4)<<2;
    int c0 = lane & 15;
    #pragma unroll
    for (int rr=0;rr<4;++rr){
        int row = blockIdx.x*16 + r0 + rr;
        if (row < nrows){
            C[(size_t)row*HID + (2*wv  )*16 + c0] = (u16)f2bfu(acc0[rr]);
            C[(size_t)row*HID + (2*wv+1)*16 + c0] = (u16)f2bfu(acc1[rr]);
        }
    }
}

extern "C" void kernel_launch(void* const* d_in, const int* in_sizes, int n_in,
                              void* d_out, int out_size, void* d_ws, size_t ws_size,
                              hipStream_t stream){
    (void)n_in; (void)out_size; (void)ws_size;
    const float* x  = (const float*)d_in[0];
    const int*  hei = (const int*)  d_in[1];
    const float* W1 = (const float*)d_in[2];
    const float* b1 = (const float*)d_in[3];
    const float* W2 = (const float*)d_in[4];
    const float* b2 = (const float*)d_in[5];
    const float* ap = (const float*)d_in[6];

    const int nN = in_sizes[0] / HID;   // 50000
    const int nE = in_sizes[1] / 2;     // 600000
    const int* nidx = hei;
    const int* eidx = hei + nE;
    const int nkeys = 2*nN;
    const int nb    = (nkeys + KPB - 1) / KPB;   // 391

    char* w = (char*)d_ws;
    size_t o = 0;
    auto alloc = [&](size_t bytes)->void*{
        void* p = (void*)(w + o);
        o += (bytes + 255) & ~(size_t)255;
        return p;
    };
    int* hist  = (int*)alloc((size_t)NBMAX*sizeof(int));
    int* bfill = (int*)alloc((size_t)NBMAX*sizeof(int));
    int* off   = (int*)alloc(((size_t)nkeys+1)*sizeof(int));
    int* csr   = (int*)alloc((size_t)2*nE*sizeof(int));
    u64* pairs = (u64*)alloc((size_t)2*nE*sizeof(u64));
    u16* bufB  = (u16*)alloc((size_t)nN*HID*sizeof(u16));   // xw / hw
    u16* bufC  = (u16*)alloc((size_t)nN*HID*sizeof(u16));   // m / m2
    u16* w1f   = (u16*)alloc((size_t)HID*HID*sizeof(u16));
    u16* w2f   = (u16*)alloc((size_t)HID*HID*sizeof(u16));

    hipMemsetAsync(hist, 0, (size_t)2*NBMAX*sizeof(int), stream);   // hist + bfill (contiguous)

    const int pgrid  = (nE + IPB - 1)/IPB;       // 293
    const int rtiles = nN/16;                    // 3125
    const int ggrid  = (rtiles + 3)/4;           // 782

    // K1: hist ∪ wfrag
    k_hist_wfrag<<<pgrid + 128, 256, 0, stream>>>(nidx, eidx, hist, nE, nN, nb, pgrid, W1, W2, w1f, w2f);
    // K2: part ∪ layer-1 gemm (fp32 A)
    k_part_gemm<<<pgrid + ggrid, 256, 0, stream>>>(nidx, eidx, hist, bfill, pairs, nE, nN, nb, pgrid,
                                                   x, w1f, bufB, nN);
    // K3: bucket (also writes off sentinel)
    k_bucket<<<nb, 256, 0, stream>>>(pairs, hist, csr, off, nkeys, nb, 2*nE);

    const int agrid = (nN + 15)/16;              // 3125

    // layer 1
    k_agg<0><<<agrid, 256, 0, stream>>>((const u32*)bufB, csr, off + nN, bufC, nullptr, nullptr, nullptr, nN);
    // fused: agg MODE-1 (h) + h @ W2 -> bufB
    k_agg1_gemm<<<agrid, 256, 0, stream>>>((const u32*)bufC, csr, off, bufB, b1, ap, w2f, nN);
    // layer 2
    k_agg<0><<<agrid, 256, 0, stream>>>((const u32*)bufB, csr, off + nN, bufC, nullptr, nullptr, nullptr, nN);
    k_agg<2><<<agrid, 256, 0, stream>>>((const u32*)bufC, csr, off, d_out, b2, x, ap, nN);
}